// Round 1
// 525.812 us; speedup vs baseline: 1.1028x; 1.1028x over previous
//
#include <hip/hip_runtime.h>
#include <hip/hip_fp16.h>

// HeteroGraphSage: 2-layer SAGEConv(mean) + PReLU + input-skip.
// N=100000, IN=D=64, E=1600000, fp32 in/out. Mean degree 16.
// R9 baseline: fp16 gather table, octet layout (8 edges / 1KB wave-load),
// two-phase tile kernel. This round:
//  (1) hist+fill fused into ONE random-atomic pass: atomicAdd(deg) returns
//      the edge's rank -> write padded CSR esort[d*64+rank] directly.
//      rank>=64 spills to a tiny overflow list (scanned in the rare tail).
//      Removes fill/bsum/scanb/rowstart kernels + one full atomic pass.
//  (2) layer_kernel LDS halved: h/x tiles stay fp16 (half2, 33-half2 row
//      stride, conflict-free) -> 50KB -> ~33.5KB -> 4 blocks/CU, occupancy
//      cap 75% -> 100% (tests latency-vs-LLC-service hypothesis on gather).

#define BLOCK 512
#define OVF_CAP 8192

struct alignas(16) h2x4 { __half2 a, b, c, d; };

// Fused counting-sort: one pass, rank from the atomic return value.
__global__ __launch_bounds__(256) void build_kernel(
    const int* __restrict__ src, const int* __restrict__ dst,
    int* __restrict__ deg, unsigned int* __restrict__ esort,
    unsigned long long* __restrict__ ovf, int* __restrict__ ovf_cnt, int E)
{
    int i = blockIdx.x * blockDim.x + threadIdx.x;
    int stride = gridDim.x * blockDim.x;
    for (int e = i; e < E; e += stride) {
        const int d = dst[e];
        const int s = src[e];
        const int r = atomicAdd(&deg[d], 1);
        if (r < 64) {
            esort[(size_t)d * 64 + r] = (unsigned int)s;
        } else {
            const int p = atomicAdd(ovf_cnt, 1);
            if (p < OVF_CAP)
                ovf[p] = ((unsigned long long)(unsigned int)d << 32)
                       | (unsigned long long)(unsigned int)s;
        }
    }
}

// fp32 -> fp16 table (m = count of float2 pairs)
__global__ __launch_bounds__(256) void cvt_half_kernel(
    const float2* __restrict__ in, __half2* __restrict__ out, int m)
{
    int i = blockIdx.x * blockDim.x + threadIdx.x;
    int stride = gridDim.x * blockDim.x;
    for (; i < m; i += stride) {
        float2 v = in[i];
        out[i] = __floats2half2_rn(v.x, v.y);
    }
}

static __device__ inline __half2 h2shfl_xor(__half2 v, int mask) {
    union { __half2 h; int i; } u; u.h = v;
    u.i = __shfl_xor(u.i, mask);
    return u.h;
}

// out = PReLU( mean_agg @ wl^T + bl + hin @ wr^T , a ) + x0 @ wskip^T + bskip
// hh: PADDED fp16 table (row n = zeros) used for gather AND the root term.
// esort: padded CSR [n][64] (first 64 edges per dst; rest in ovf).
__global__ __launch_bounds__(BLOCK) void layer_kernel(
    const int* __restrict__ deg, const unsigned int* __restrict__ esort,
    const unsigned long long* __restrict__ ovf, const int* __restrict__ ovf_cnt,
    const __half* __restrict__ hh, const float* __restrict__ x0,
    const float* __restrict__ wl, const float* __restrict__ bl,
    const float* __restrict__ wr, const float* __restrict__ wskip,
    const float* __restrict__ bskip, const float* __restrict__ aprelu,
    float* __restrict__ out_f, __half* __restrict__ out_h, int n)
{
    // agg stays fp32 (stride 65 dwords -> 2-way banks, free).
    // h/x tiles in fp16: row stride 33 half2 (=66 halves) -> (lane+c)%32
    // bank pattern, 2-way, free. LDS total ~33.5KB -> 4 blocks/CU.
    __shared__ float   agg_s[64 * 65];
    __shared__ __half2 h_s2[64 * 33];
    __shared__ __half2 x_s2[64 * 33];

    const int tid  = threadIdx.x;
    const int lane = tid & 63;
    const int wvu  = __builtin_amdgcn_readfirstlane(tid >> 6);  // 0..7
    const int o    = lane >> 3;   // edge octet 0..7
    const int g    = lane & 7;    // 16B chunk of the 128B fp16 row

    const int tileBase = blockIdx.x * 64;
    const int tileEnd  = min(tileBase + 64, n);

    const __half2 z2 = __floats2half2_rn(0.f, 0.f);

    // stage root (fp16, straight copy) and skip (fp32 -> fp16)
    const __half2* hh2 = (const __half2*)hh;
    const float2*  x02 = (const float2*)x0;
    for (int i = tid; i < 64 * 32; i += BLOCK) {
        const int nl = i >> 5, c2 = i & 31;
        const int node = tileBase + nl;
        __half2 hv = z2, xv = z2;
        if (node < n) {
            hv = hh2[(size_t)node * 32 + c2];
            const float2 t = x02[(size_t)node * 32 + c2];
            xv = __floats2half2_rn(t.x, t.y);
        }
        h_s2[nl * 33 + c2] = hv;
        x_s2[nl * 33 + c2] = xv;
    }

    // ---- Phase A: wave owns nodes n0..n0+7; 8 edges per 1KB load.
    const int n0 = tileBase + wvu * 8;
    int dg_k[8];
#pragma unroll
    for (int k = 0; k < 8; k++) {
        const int nd = n0 + k;
        dg_k[k] = (nd < tileEnd) ? deg[nd] : 0;
    }

    unsigned int ew[8];
#pragma unroll
    for (int k = 0; k < 8; k++) {
        unsigned int w = (unsigned int)n;            // zero-row sentinel
        const int dc = min(dg_k[k], 64);
        if (lane < dc) w = esort[(size_t)(n0 + k) * 64 + lane];
        ew[k] = w;
    }

    __half2 acc[8][4];
#pragma unroll
    for (int k = 0; k < 8; k++) {
        acc[k][0] = z2; acc[k][1] = z2; acc[k][2] = z2; acc[k][3] = z2;
    }

    int mx = 0;
#pragma unroll
    for (int k = 0; k < 8; k++) mx = max(mx, min(dg_k[k], 64));

    const h2x4* tab = (const h2x4*)hh;   // row = 8 chunks of 16B
    for (int j = 0; j < mx; j += 8) {
#pragma unroll
        for (int k = 0; k < 8; k++) {
            const int r0 = __builtin_amdgcn_readlane((int)ew[k], j + 0);
            const int r1 = __builtin_amdgcn_readlane((int)ew[k], j + 1);
            const int r2 = __builtin_amdgcn_readlane((int)ew[k], j + 2);
            const int r3 = __builtin_amdgcn_readlane((int)ew[k], j + 3);
            const int r4 = __builtin_amdgcn_readlane((int)ew[k], j + 4);
            const int r5 = __builtin_amdgcn_readlane((int)ew[k], j + 5);
            const int r6 = __builtin_amdgcn_readlane((int)ew[k], j + 6);
            const int r7 = __builtin_amdgcn_readlane((int)ew[k], j + 7);
            int s = r0;
            s = (o == 1) ? r1 : s; s = (o == 2) ? r2 : s;
            s = (o == 3) ? r3 : s; s = (o == 4) ? r4 : s;
            s = (o == 5) ? r5 : s; s = (o == 6) ? r6 : s;
            s = (o == 7) ? r7 : s;
            const h2x4 v = tab[(size_t)s * 8 + g];   // one 128B line per edge
            acc[k][0] = __hadd2(acc[k][0], v.a);
            acc[k][1] = __hadd2(acc[k][1], v.b);
            acc[k][2] = __hadd2(acc[k][2], v.c);
            acc[k][3] = __hadd2(acc[k][3], v.d);
        }
    }

    // rare tail: deg > 64 -> remaining edges live in the overflow list.
    int anyovf = 0;
#pragma unroll
    for (int k = 0; k < 8; k++) anyovf |= (int)(dg_k[k] > 64);
    if (anyovf) {
        const int cnt = min(*ovf_cnt, OVF_CAP);
#pragma unroll
        for (int k = 0; k < 8; k++) {
            if (dg_k[k] > 64) {
                const int nd = n0 + k;
                for (int i2 = 0; i2 < cnt; i2++) {
                    const unsigned long long ev = ovf[i2];
                    if ((int)(ev >> 32) == nd && o == 0) {
                        // octet 0 only: counted once after the xor-reduce
                        const h2x4 v = tab[(size_t)(unsigned int)ev * 8 + g];
                        acc[k][0] = __hadd2(acc[k][0], v.a);
                        acc[k][1] = __hadd2(acc[k][1], v.b);
                        acc[k][2] = __hadd2(acc[k][2], v.c);
                        acc[k][3] = __hadd2(acc[k][3], v.d);
                    }
                }
            }
        }
    }

    // flush: reduce across octets (xor 8,16,32); lane (o,g) owns feature 8g+o
#pragma unroll
    for (int k = 0; k < 8; k++) {
        const int nd = n0 + k;
        if (nd < tileEnd) {
            __half2 a0 = acc[k][0], a1 = acc[k][1], a2 = acc[k][2], a3 = acc[k][3];
#pragma unroll
            for (int m = 8; m <= 32; m <<= 1) {
                a0 = __hadd2(a0, h2shfl_xor(a0, m));
                a1 = __hadd2(a1, h2shfl_xor(a1, m));
                a2 = __hadd2(a2, h2shfl_xor(a2, m));
                a3 = __hadd2(a3, h2shfl_xor(a3, m));
            }
            const __half2 sel2 = (o >= 6) ? a3 : (o >= 4) ? a2 : (o >= 2) ? a1 : a0;
            const float hv = (o & 1) ? __high2float(sel2) : __low2float(sel2);
            const float inv = 1.0f / fmaxf((float)dg_k[k], 1.0f);
            agg_s[(nd - tileBase) * 65 + 8 * g + o] = hv * inv;
        }
    }
    __syncthreads();

    // ---- Phase B: dense. lane = node; wave covers dims [wvu*8, wvu*8+8).
    float acc1[8], acc2[8], acc3[8];
#pragma unroll
    for (int dd = 0; dd < 8; dd++) { acc1[dd] = 0.f; acc2[dd] = 0.f; acc3[dd] = 0.f; }

    for (int kc = 0; kc < 8; kc++) {
        float ak[8], hk[8], xk[8];
#pragma unroll
        for (int k = 0; k < 8; k++) ak[k] = agg_s[lane * 65 + kc * 8 + k];
        const __half2* hrow = h_s2 + lane * 33 + kc * 4;
        const __half2* xrow = x_s2 + lane * 33 + kc * 4;
#pragma unroll
        for (int k2 = 0; k2 < 4; k2++) {
            const float2 hv = __half22float2(hrow[k2]);
            hk[2 * k2]     = hv.x;
            hk[2 * k2 + 1] = hv.y;
            const float2 xv = __half22float2(xrow[k2]);
            xk[2 * k2]     = xv.x;
            xk[2 * k2 + 1] = xv.y;
        }
#pragma unroll
        for (int dd = 0; dd < 8; dd++) {
            const int d = wvu * 8 + dd;            // wave-uniform -> s_loads
            const float* wlr = wl    + d * 64 + kc * 8;
            const float* wrr = wr    + d * 64 + kc * 8;
            const float* wsr = wskip + d * 64 + kc * 8;
#pragma unroll
            for (int k = 0; k < 8; k++) {
                acc1[dd] += ak[k] * wlr[k];
                acc2[dd] += hk[k] * wrr[k];
                acc3[dd] += xk[k] * wsr[k];
            }
        }
    }
    __syncthreads();   // all waves done reading agg_s before alias-write

    float* out_s = agg_s;
#pragma unroll
    for (int dd = 0; dd < 8; dd++) {
        const int d = wvu * 8 + dd;
        float z = acc1[dd] + acc2[dd] + bl[d];
        z = (z >= 0.f) ? z : aprelu[d] * z;
        out_s[lane * 65 + d] = z + acc3[dd] + bskip[d];
    }
    __syncthreads();

    for (int i = tid; i < 64 * 64; i += BLOCK) {
        const int nl = i >> 6, d = i & 63;
        const int nd = tileBase + nl;
        if (nd < n) {
            const float v = out_s[nl * 65 + d];
            if (out_h) out_h[(size_t)nd * 64 + d] = __float2half(v);
            else       out_f[(size_t)nd * 64 + d] = v;
        }
    }
}

extern "C" void kernel_launch(void* const* d_in, const int* in_sizes, int n_in,
                              void* d_out, int out_size, void* d_ws, size_t ws_size,
                              hipStream_t stream)
{
    const float* x   = (const float*)d_in[0];
    const int*   ei  = (const int*)d_in[1];
    const float* wl0 = (const float*)d_in[2];
    const float* bl0 = (const float*)d_in[3];
    const float* wr0 = (const float*)d_in[4];
    const float* ws0 = (const float*)d_in[5];
    const float* bs0 = (const float*)d_in[6];
    const float* a0  = (const float*)d_in[7];
    const float* wl1 = (const float*)d_in[8];
    const float* bl1 = (const float*)d_in[9];
    const float* wr1 = (const float*)d_in[10];
    const float* ws1 = (const float*)d_in[11];
    const float* bs1 = (const float*)d_in[12];
    const float* a1  = (const float*)d_in[13];

    const int n = in_sizes[0] / 64;
    const int E = in_sizes[1] / 2;
    const int* src = ei;
    const int* dst = ei + E;

    // workspace layout (all 16B-aligned given n=100000):
    int* deg                = (int*)d_ws;                              // n ints
    int* ovf_cnt            = deg + n;                                 // 4 ints
    unsigned long long* ovf = (unsigned long long*)(ovf_cnt + 4);      // OVF_CAP u64
    unsigned int* esort     = (unsigned int*)(ovf + OVF_CAP);          // n*64 u32 (padded CSR)
    __half* xh              = (__half*)(esort + (size_t)n * 64);       // (n+1)*64, row n=0
    __half* h1h             = xh + (size_t)(n + 1) * 64;               // (n+1)*64, row n=0

    // zero deg + ovf_cnt in one shot; zero the sentinel rows
    hipMemsetAsync(deg, 0, (size_t)n * sizeof(int) + 4 * sizeof(int), stream);
    hipMemsetAsync(xh  + (size_t)n * 64, 0, 64 * sizeof(__half), stream);
    hipMemsetAsync(h1h + (size_t)n * 64, 0, 64 * sizeof(__half), stream);

    cvt_half_kernel<<<1024, 256, 0, stream>>>(
        (const float2*)x, (__half2*)xh, n * 32);
    build_kernel<<<2048, 256, 0, stream>>>(src, dst, deg, esort, ovf, ovf_cnt, E);

    const int ntiles = (n + 63) / 64;

    layer_kernel<<<ntiles, BLOCK, 0, stream>>>(deg, esort, ovf, ovf_cnt,
        xh, x, wl0, bl0, wr0, ws0, bs0, a0, nullptr, h1h, n);
    layer_kernel<<<ntiles, BLOCK, 0, stream>>>(deg, esort, ovf, ovf_cnt,
        h1h, x, wl1, bl1, wr1, ws1, bs1, a1, (float*)d_out, nullptr, n);
}

// Round 2
// 419.134 us; speedup vs baseline: 1.3834x; 1.2545x over previous
//
#include <hip/hip_runtime.h>
#include <hip/hip_fp16.h>

// HeteroGraphSage: 2-layer SAGEConv(mean) + PReLU + input-skip.
// N=100000, IN=D=64, E=1600000, fp32 in/out. Mean degree 16.
// R2:
//  (1) layer gather: sentinel loads eliminated. deg is wave-uniform per k ->
//      scalar skip of whole (j,k) octet groups + per-lane tail predication.
//      readlane+cndmask broadcast chain -> one ds_bpermute (__shfl).
//      Cuts issued line-transactions ~33% (the measured ~16G lines/s wall).
//  (2) build: two-pass LDS-binned counting sort replaces the 150us
//      random-atomic pass. Pass1 bins (dst,src) into 391 buckets of 256
//      nodes (LDS hist + one global atomic per block-bucket, packed
//      (dloc<<17)|src u32). Pass2: one block per bucket, LDS counters,
//      scatter esort inside an L2-resident 64KB window, coalesced deg.
//      bucket[] aliases h1h (dead until layer0).

#define BLOCK 512
#define OVF_CAP 8192
#define BSHIFT 8                    // 256 nodes per bucket
#define BCAP 8000                   // mean 4092, +61 sigma; fits under h1h

struct alignas(16) h2x4 { __half2 a, b, c, d; };

// ---- build pass 1: bin edges by dst>>8 with per-block LDS histogram.
#define P1_CHUNK 4096
__global__ __launch_bounds__(256) void bin_kernel(
    const int* __restrict__ src, const int* __restrict__ dst,
    int* __restrict__ bcnt, unsigned int* __restrict__ bucket,
    int NB, int E)
{
    __shared__ int cnt[512];
    __shared__ int base[512];
    const int tid = threadIdx.x;
    const int e0  = blockIdx.x * P1_CHUNK;

    for (int i = tid; i < NB; i += 256) cnt[i] = 0;
    __syncthreads();

    int dv[16], sv[16];
#pragma unroll
    for (int u = 0; u < 16; u++) {
        const int e = e0 + u * 256 + tid;
        if (e < E) { dv[u] = dst[e]; sv[u] = src[e]; }
        else       { dv[u] = -1; sv[u] = 0; }
    }
#pragma unroll
    for (int u = 0; u < 16; u++)
        if (dv[u] >= 0) atomicAdd(&cnt[dv[u] >> BSHIFT], 1);
    __syncthreads();

    for (int i = tid; i < NB; i += 256) {
        const int c = cnt[i];
        base[i] = (c > 0) ? atomicAdd(&bcnt[i], c) : 0;
        cnt[i]  = 0;
    }
    __syncthreads();

#pragma unroll
    for (int u = 0; u < 16; u++) {
        if (dv[u] >= 0) {
            const int b = dv[u] >> BSHIFT;
            const int r = atomicAdd(&cnt[b], 1);
            const int pos = base[b] + r;
            if (pos < BCAP)
                bucket[(size_t)b * BCAP + pos] =
                    ((unsigned int)(dv[u] & 255) << 17) | (unsigned int)sv[u];
        }
    }
}

// ---- build pass 2: one block per bucket -> padded CSR + deg.
__global__ __launch_bounds__(256) void csr_kernel(
    const int* __restrict__ bcnt, const unsigned int* __restrict__ bucket,
    int* __restrict__ deg, unsigned int* __restrict__ esort,
    unsigned long long* __restrict__ ovf, int* __restrict__ ovf_cnt, int n)
{
    __shared__ int cnt2[256];
    const int b   = blockIdx.x;
    const int tid = threadIdx.x;
    cnt2[tid] = 0;
    __syncthreads();

    const int m     = min(bcnt[b], BCAP);
    const int nbase = b << BSHIFT;
    for (int i = tid; i < m; i += 256) {
        const unsigned int e = bucket[(size_t)b * BCAP + i];
        const int dloc = (int)(e >> 17);
        const int s    = (int)(e & 0x1FFFF);
        const int r    = atomicAdd(&cnt2[dloc], 1);
        if (r < 64) {
            esort[(size_t)(nbase + dloc) * 64 + r] = (unsigned int)s;
        } else {
            const int p = atomicAdd(ovf_cnt, 1);
            if (p < OVF_CAP)
                ovf[p] = ((unsigned long long)(unsigned int)(nbase + dloc) << 32)
                       | (unsigned long long)(unsigned int)s;
        }
    }
    __syncthreads();
    const int node = nbase + tid;
    if (node < n) deg[node] = cnt2[tid];
}

// fp32 -> fp16 table (m = count of float2 pairs)
__global__ __launch_bounds__(256) void cvt_half_kernel(
    const float2* __restrict__ in, __half2* __restrict__ out, int m)
{
    int i = blockIdx.x * blockDim.x + threadIdx.x;
    int stride = gridDim.x * blockDim.x;
    for (; i < m; i += stride) {
        float2 v = in[i];
        out[i] = __floats2half2_rn(v.x, v.y);
    }
}

static __device__ inline __half2 h2shfl_xor(__half2 v, int mask) {
    union { __half2 h; int i; } u; u.h = v;
    u.i = __shfl_xor(u.i, mask);
    return u.h;
}

// out = PReLU( mean_agg @ wl^T + bl + hin @ wr^T , a ) + x0 @ wskip^T + bskip
__global__ __launch_bounds__(BLOCK) void layer_kernel(
    const int* __restrict__ deg, const unsigned int* __restrict__ esort,
    const unsigned long long* __restrict__ ovf, const int* __restrict__ ovf_cnt,
    const __half* __restrict__ hh, const float* __restrict__ x0,
    const float* __restrict__ wl, const float* __restrict__ bl,
    const float* __restrict__ wr, const float* __restrict__ wskip,
    const float* __restrict__ bskip, const float* __restrict__ aprelu,
    float* __restrict__ out_f, __half* __restrict__ out_h, int n)
{
    __shared__ float   agg_s[64 * 65];
    __shared__ __half2 h_s2[64 * 33];
    __shared__ __half2 x_s2[64 * 33];

    const int tid  = threadIdx.x;
    const int lane = tid & 63;
    const int wvu  = __builtin_amdgcn_readfirstlane(tid >> 6);  // 0..7
    const int o    = lane >> 3;   // edge octet 0..7
    const int g    = lane & 7;    // 16B chunk of the 128B fp16 row

    const int tileBase = blockIdx.x * 64;
    const int tileEnd  = min(tileBase + 64, n);

    const __half2 z2 = __floats2half2_rn(0.f, 0.f);

    // stage root (fp16, straight copy) and skip (fp32 -> fp16)
    const __half2* hh2 = (const __half2*)hh;
    const float2*  x02 = (const float2*)x0;
    for (int i = tid; i < 64 * 32; i += BLOCK) {
        const int nl = i >> 5, c2 = i & 31;
        const int node = tileBase + nl;
        __half2 hv = z2, xv = z2;
        if (node < n) {
            hv = hh2[(size_t)node * 32 + c2];
            const float2 t = x02[(size_t)node * 32 + c2];
            xv = __floats2half2_rn(t.x, t.y);
        }
        h_s2[nl * 33 + c2] = hv;
        x_s2[nl * 33 + c2] = xv;
    }

    // ---- Phase A: wave owns nodes n0..n0+7; 8 edges per 1KB load.
    const int n0 = tileBase + wvu * 8;
    int dg_k[8], dgc_k[8];
#pragma unroll
    for (int k = 0; k < 8; k++) {
        const int nd = n0 + k;
        dg_k[k]  = (nd < tileEnd) ? deg[nd] : 0;
        dgc_k[k] = __builtin_amdgcn_readfirstlane(min(dg_k[k], 64)); // scalar
    }

    unsigned int ew[8];
#pragma unroll
    for (int k = 0; k < 8; k++) {
        unsigned int w = (unsigned int)n;
        if (lane < dgc_k[k]) w = esort[(size_t)(n0 + k) * 64 + lane];
        ew[k] = w;
    }

    __half2 acc[8][4];
#pragma unroll
    for (int k = 0; k < 8; k++) {
        acc[k][0] = z2; acc[k][1] = z2; acc[k][2] = z2; acc[k][3] = z2;
    }

    int mx = 0;
#pragma unroll
    for (int k = 0; k < 8; k++) mx = max(mx, dgc_k[k]);

    const h2x4* tab = (const h2x4*)hh;   // row = 8 chunks of 16B
    const int jo = o;                    // per-lane octet offset
    for (int j = 0; j < mx; j += 8) {
#pragma unroll
        for (int k = 0; k < 8; k++) {
            const int dgk = dgc_k[k];          // scalar
            if (j < dgk) {                     // uniform: skip dead octet groups
                const int s = __shfl((int)ew[k], j + jo);   // ds_bpermute
                if (j + jo < dgk) {            // per-lane: no sentinel requests
                    const h2x4 v = tab[(size_t)(s * 8 + g)];
                    acc[k][0] = __hadd2(acc[k][0], v.a);
                    acc[k][1] = __hadd2(acc[k][1], v.b);
                    acc[k][2] = __hadd2(acc[k][2], v.c);
                    acc[k][3] = __hadd2(acc[k][3], v.d);
                }
            }
        }
    }

    // rare tail: deg > 64 -> remaining edges live in the overflow list.
    int anyovf = 0;
#pragma unroll
    for (int k = 0; k < 8; k++) anyovf |= (int)(dg_k[k] > 64);
    if (anyovf) {
        const int cnt = min(*ovf_cnt, OVF_CAP);
#pragma unroll
        for (int k = 0; k < 8; k++) {
            if (dg_k[k] > 64) {
                const int nd = n0 + k;
                for (int i2 = 0; i2 < cnt; i2++) {
                    const unsigned long long ev = ovf[i2];
                    if ((int)(ev >> 32) == nd && o == 0) {
                        const h2x4 v = tab[(size_t)(unsigned int)ev * 8 + g];
                        acc[k][0] = __hadd2(acc[k][0], v.a);
                        acc[k][1] = __hadd2(acc[k][1], v.b);
                        acc[k][2] = __hadd2(acc[k][2], v.c);
                        acc[k][3] = __hadd2(acc[k][3], v.d);
                    }
                }
            }
        }
    }

    // flush: reduce across octets (xor 8,16,32); lane (o,g) owns feature 8g+o
#pragma unroll
    for (int k = 0; k < 8; k++) {
        const int nd = n0 + k;
        if (nd < tileEnd) {
            __half2 a0 = acc[k][0], a1 = acc[k][1], a2 = acc[k][2], a3 = acc[k][3];
#pragma unroll
            for (int m = 8; m <= 32; m <<= 1) {
                a0 = __hadd2(a0, h2shfl_xor(a0, m));
                a1 = __hadd2(a1, h2shfl_xor(a1, m));
                a2 = __hadd2(a2, h2shfl_xor(a2, m));
                a3 = __hadd2(a3, h2shfl_xor(a3, m));
            }
            const __half2 sel2 = (o >= 6) ? a3 : (o >= 4) ? a2 : (o >= 2) ? a1 : a0;
            const float hv = (o & 1) ? __high2float(sel2) : __low2float(sel2);
            const float inv = 1.0f / fmaxf((float)dg_k[k], 1.0f);
            agg_s[(nd - tileBase) * 65 + 8 * g + o] = hv * inv;
        }
    }
    __syncthreads();

    // ---- Phase B: dense. lane = node; wave covers dims [wvu*8, wvu*8+8).
    float acc1[8], acc2[8], acc3[8];
#pragma unroll
    for (int dd = 0; dd < 8; dd++) { acc1[dd] = 0.f; acc2[dd] = 0.f; acc3[dd] = 0.f; }

    for (int kc = 0; kc < 8; kc++) {
        float ak[8], hk[8], xk[8];
#pragma unroll
        for (int k = 0; k < 8; k++) ak[k] = agg_s[lane * 65 + kc * 8 + k];
        const __half2* hrow = h_s2 + lane * 33 + kc * 4;
        const __half2* xrow = x_s2 + lane * 33 + kc * 4;
#pragma unroll
        for (int k2 = 0; k2 < 4; k2++) {
            const float2 hv = __half22float2(hrow[k2]);
            hk[2 * k2]     = hv.x;
            hk[2 * k2 + 1] = hv.y;
            const float2 xv = __half22float2(xrow[k2]);
            xk[2 * k2]     = xv.x;
            xk[2 * k2 + 1] = xv.y;
        }
#pragma unroll
        for (int dd = 0; dd < 8; dd++) {
            const int d = wvu * 8 + dd;            // wave-uniform -> s_loads
            const float* wlr = wl    + d * 64 + kc * 8;
            const float* wrr = wr    + d * 64 + kc * 8;
            const float* wsr = wskip + d * 64 + kc * 8;
#pragma unroll
            for (int k = 0; k < 8; k++) {
                acc1[dd] += ak[k] * wlr[k];
                acc2[dd] += hk[k] * wrr[k];
                acc3[dd] += xk[k] * wsr[k];
            }
        }
    }
    __syncthreads();   // all waves done reading agg_s before alias-write

    float* out_s = agg_s;
#pragma unroll
    for (int dd = 0; dd < 8; dd++) {
        const int d = wvu * 8 + dd;
        float z = acc1[dd] + acc2[dd] + bl[d];
        z = (z >= 0.f) ? z : aprelu[d] * z;
        out_s[lane * 65 + d] = z + acc3[dd] + bskip[d];
    }
    __syncthreads();

    for (int i = tid; i < 64 * 64; i += BLOCK) {
        const int nl = i >> 6, d = i & 63;
        const int nd = tileBase + nl;
        if (nd < n) {
            const float v = out_s[nl * 65 + d];
            if (out_h) out_h[(size_t)nd * 64 + d] = __float2half(v);
            else       out_f[(size_t)nd * 64 + d] = v;
        }
    }
}

extern "C" void kernel_launch(void* const* d_in, const int* in_sizes, int n_in,
                              void* d_out, int out_size, void* d_ws, size_t ws_size,
                              hipStream_t stream)
{
    const float* x   = (const float*)d_in[0];
    const int*   ei  = (const int*)d_in[1];
    const float* wl0 = (const float*)d_in[2];
    const float* bl0 = (const float*)d_in[3];
    const float* wr0 = (const float*)d_in[4];
    const float* ws0 = (const float*)d_in[5];
    const float* bs0 = (const float*)d_in[6];
    const float* a0  = (const float*)d_in[7];
    const float* wl1 = (const float*)d_in[8];
    const float* bl1 = (const float*)d_in[9];
    const float* wr1 = (const float*)d_in[10];
    const float* ws1 = (const float*)d_in[11];
    const float* bs1 = (const float*)d_in[12];
    const float* a1  = (const float*)d_in[13];

    const int n = in_sizes[0] / 64;
    const int E = in_sizes[1] / 2;
    const int* src = ei;
    const int* dst = ei + E;

    const int NB = (n + 255) >> BSHIFT;   // 391 for n=100000 (<=512)

    // workspace layout:
    int* deg                = (int*)d_ws;                              // n
    int* bcnt               = deg + n;                                 // 512
    int* ovf_cnt            = bcnt + 512;                              // 4
    unsigned long long* ovf = (unsigned long long*)(ovf_cnt + 4);      // OVF_CAP
    unsigned int* esort     = (unsigned int*)(ovf + OVF_CAP);          // n*64
    __half* xh              = (__half*)(esort + (size_t)n * 64);       // (n+1)*64
    __half* h1h             = xh + (size_t)(n + 1) * 64;               // (n+1)*64
    unsigned int* bucket    = (unsigned int*)h1h;  // ALIAS: dead until layer0
    // NB*BCAP*4 = 391*8000*4 = 12.51MB <= (n+1)*128 = 12.81MB  ✓

    hipMemsetAsync(bcnt, 0, (512 + 4) * sizeof(int), stream);          // bcnt+ovf_cnt
    hipMemsetAsync(xh + (size_t)n * 64, 0, 64 * sizeof(__half), stream);

    cvt_half_kernel<<<1024, 256, 0, stream>>>(
        (const float2*)x, (__half2*)xh, n * 32);

    const int nb1 = (E + P1_CHUNK - 1) / P1_CHUNK;   // 391
    bin_kernel<<<nb1, 256, 0, stream>>>(src, dst, bcnt, bucket, NB, E);
    csr_kernel<<<NB, 256, 0, stream>>>(bcnt, bucket, deg, esort, ovf, ovf_cnt, n);

    // bucket is dead now; zero h1h sentinel row before layer0 writes h1h.
    hipMemsetAsync(h1h + (size_t)n * 64, 0, 64 * sizeof(__half), stream);

    const int ntiles = (n + 63) / 64;

    layer_kernel<<<ntiles, BLOCK, 0, stream>>>(deg, esort, ovf, ovf_cnt,
        xh, x, wl0, bl0, wr0, ws0, bs0, a0, nullptr, h1h, n);
    layer_kernel<<<ntiles, BLOCK, 0, stream>>>(deg, esort, ovf, ovf_cnt,
        h1h, x, wl1, bl1, wr1, ws1, bs1, a1, (float*)d_out, nullptr, n);
}